// Round 11
// baseline (420.722 us; speedup 1.0000x reference)
//
#include <hip/hip_runtime.h>
#include <math.h>

#define BATCH  8
#define SEQLEN 4096
#define HID    1024
#define STATE  64
#define NC     16
#define TC     (SEQLEN / NC)   // 256 steps per chunk
#define TT     32              // time rows per LDS tile (scalar path)
#define NTILE  (TC / TT)
#define DBLK   64
#define NS     16
#define NP     8
#define RB     8

typedef float f32x2 __attribute__((ext_vector_type(2)));
typedef float f32x4 __attribute__((ext_vector_type(4)));
typedef short bf16x8 __attribute__((ext_vector_type(8)));
typedef short bf16x8u __attribute__((ext_vector_type(8), aligned(4)));

// ws layout (bytes)
#define WS_PA  0
#define WS_PW  (256 * 1024)
#define WS_PE  (512 * 1024)
#define WS_KR  (1024 * 1024)          // ushort[1024][2][528]  = 2.16 MB
#define WS_ZL  (4  * 1024 * 1024)     // f32, 15*8*1024*64*4   = 31.5 MB
#define WS_ZT  (36 * 1024 * 1024)     // ushort[1024][128][64] = 16 MB
#define WS_W2  (52 * 1024 * 1024)     // ushort[1024][256][64] = 32 MB
#define WS_NEED (85ull * 1024 * 1024)

__device__ __forceinline__ unsigned short f2bf(float x) {
    unsigned int u = __builtin_bit_cast(unsigned int, x);
    u = (u + 0x7FFFu + ((u >> 16) & 1u)) >> 16;
    return (unsigned short)u;
}

__device__ __forceinline__ void gload_lds16(const float* g, float* l) {
    __builtin_amdgcn_global_load_lds((const __attribute__((address_space(1))) void*)g,
                                     (__attribute__((address_space(3))) void*)l,
                                     16, 0, 0);
}

__device__ __forceinline__ float quad_reduce_add(float y) {
    int t = __builtin_amdgcn_mov_dpp(__builtin_bit_cast(int, y), 0xB1, 0xF, 0xF, true);
    y += __builtin_bit_cast(float, t);
    t = __builtin_amdgcn_mov_dpp(__builtin_bit_cast(int, y), 0x4E, 0xF, 0xF, true);
    y += __builtin_bit_cast(float, t);
    return y;
}

// ---------------------------------------------------------------- K0: params
__global__ void k0_params(const float* __restrict__ A, const float* __restrict__ Bm,
                          const float* __restrict__ C, const float* __restrict__ dt,
                          float* __restrict__ pa, float* __restrict__ pw,
                          float* __restrict__ pE) {
    int i = blockIdx.x * 256 + threadIdx.x;
    if (i >= HID * STATE) return;
    int n = i & (STATE - 1);
    float aexp = expf(A[i]);
    float dtn  = dt[n];
    float a    = expf(-aexp * dtn);
    pa[i] = a;
    pw[i] = C[i] * (Bm[i] * (1.0f - a) / aexp);
    pE[i] = expf(-aexp * dtn * (float)TC);
}

// ------------------------------------------- kKR: reversed conv-kernel tables
// KR2[d][0][i] = K_d(255-i) (0 if out of range), KR2[d][1][i] = K_d(254-i).
// Dv folded into K(0). 1024 blocks x 64 threads.
__global__ void k_kr(const float* __restrict__ pa, const float* __restrict__ pw,
                     const float* __restrict__ Dv, unsigned short* __restrict__ KR2) {
    __shared__ float K[256];
    int d = blockIdx.x, n = threadIdx.x;
    float a = pa[d * 64 + n];
    float v = pw[d * 64 + n];
    float dvd = Dv[d];
    for (int t = 0; t < 256; t++) {
        float s = v;
        #pragma unroll
        for (int off = 1; off < 64; off <<= 1) s += __shfl_xor(s, off);
        if (n == 0) K[t] = s + (t == 0 ? dvd : 0.0f);
        v *= a;
    }
    __syncthreads();
    unsigned short* kd = KR2 + (size_t)d * 1056;
    for (int i = n; i < 528; i += 64) {
        int x0 = 255 - i;
        int x1 = 254 - i;
        kd[i]       = (x0 >= 0) ? f2bf(K[x0]) : 0;
        kd[528 + i] = (x1 >= 0) ? f2bf(K[x1]) : 0;
    }
}

// ------------------------------------------- kW2: W2[d][t][n] = w_n * a_n^{t+1}
__global__ void k_w2(const float* __restrict__ pa, const float* __restrict__ pw,
                     unsigned short* __restrict__ W2) {
    int d = blockIdx.x, n = threadIdx.x;   // 64 threads
    float a = pa[d * 64 + n];
    float v = pw[d * 64 + n] * a;
    unsigned short* wd = W2 + (size_t)d * 256 * 64 + n;
    for (int t = 0; t < 256; t++) { wd[(size_t)t * 64] = f2bf(v); v *= a; }
}

// ------------------------------------------- K1: chunk-local end states (scalar, proven)
__global__ __launch_bounds__(256, 3) void k1_locals(const float* __restrict__ u,
                                                    const float* __restrict__ pa,
                                                    float* __restrict__ zl) {
    __shared__ float utile[2][TT * DBLK];
    int bid  = blockIdx.x;
    int dset = bid & 15;
    int b    = (bid >> 4) & 7;
    int c    = bid >> 7;
    int w    = threadIdx.x >> 6;
    int lane = threadIdx.x & 63;
    int dl   = lane >> 2, p = lane & 3;
    int d    = dset * DBLK + w * 16 + dl;

    f32x2 a2[NP], z2[NP];
    {
        const f32x2* pap = (const f32x2*)(pa + (size_t)d * STATE + p * NS);
        #pragma unroll
        for (int j = 0; j < NP; j++) a2[j] = pap[j];
    }
    #pragma unroll
    for (int j = 0; j < NP; j++) { z2[j].x = 0.f; z2[j].y = 0.f; }

    const char* ubase = (const char*)(u + ((size_t)b * SEQLEN + (size_t)c * TC) * HID
                                        + (size_t)dset * DBLK);

    #define ISSUE_TILE(t, buf)                                                        \
        {                                                                             \
            _Pragma("unroll")                                                         \
            for (int k = 0; k < 2; k++) {                                             \
                int off = w * 2048 + k * 1024 + lane * 16;                            \
                int row = off >> 8;                                                   \
                int col = off & 255;                                                  \
                const float* src = (const float*)(ubase + ((size_t)((t) * TT + row)) * (HID * 4) + col); \
                float* dst = &utile[buf][w * 512 + k * 256];                           \
                gload_lds16(src, dst);                                                \
            }                                                                         \
        }

    ISSUE_TILE(0, 0);
    __syncthreads();
    int cur = 0;
    for (int tile = 0; tile < NTILE; ++tile) {
        if (tile + 1 < NTILE) ISSUE_TILE(tile + 1, cur ^ 1);
        const float* ut = &utile[cur][w * 16 + dl];
        #pragma unroll
        for (int r = 0; r < TT; r++) {
            float uss = ut[r * DBLK];
            f32x2 us; us.x = uss; us.y = uss;
            #pragma unroll
            for (int j = 0; j < NP; j++)
                z2[j] = __builtin_elementwise_fma(a2[j], z2[j], us);
        }
        __syncthreads();
        cur ^= 1;
    }

    f32x2* zp = (f32x2*)(zl + (((size_t)c * BATCH + b) * HID + d) * STATE + p * NS);
    #pragma unroll
    for (int j = 0; j < NP; j++) zp[j] = z2[j];
}

// ---------------------------------- K2: prefix scan over chunks
__global__ void k2_scan(const float* __restrict__ pE, float* __restrict__ zl) {
    int i  = blockIdx.x * 256 + threadIdx.x;
    int dn = i & (HID * STATE - 1);
    float E = pE[dn];
    size_t stride = (size_t)BATCH * HID * STATE;
    float g = zl[i];
    for (int c = 1; c < NC - 1; c++) {
        float v = zl[i + c * stride];
        g = fmaf(E, g, v);
        zl[i + c * stride] = g;
    }
}

// ---------------------------------- kZT: ZT[d][bc=b*16+c][n] bf16 chunk-init states
__global__ void k_zt(const float* __restrict__ zl, unsigned short* __restrict__ ZT) {
    int idx = blockIdx.x * 256 + threadIdx.x;   // d*8192 + bc*64 + n
    int n  = idx & 63;
    int bc = (idx >> 6) & 127;
    int d  = idx >> 13;
    int b = bc >> 4, c = bc & 15;
    float z = 0.0f;
    if (c > 0)
        z = zl[((size_t)((c - 1) * 8 + b) * 1024 + d) * 64 + n];
    ZT[idx] = f2bf(z);
}

// ---------------------------------- K3 MFMA: Toeplitz conv + state correction
// block: (dg of 16 d, bcg of 16 bc, th t-half). 512 thr = 8 waves, wave owns 2 d's.
__global__ __launch_bounds__(512, 2) void k3_mfma(const float* __restrict__ u,
                                                  const unsigned short* __restrict__ KR2,
                                                  const unsigned short* __restrict__ W2,
                                                  const unsigned short* __restrict__ ZT,
                                                  float* __restrict__ out) {
    __shared__ float ulds[2][32 * 256];   // [s][bc][d-swizzled] f32, 32 KB each
    int bid = blockIdx.x;
    int dg  = bid & 63;
    int bcg = (bid >> 6) & 7;
    int th  = bid >> 9;
    int tid = threadIdx.x;
    int w   = tid >> 6;          // wave 0..7
    int l   = tid & 63;
    int g   = l >> 4;            // 0..3
    int r16 = l & 15;

    // staging lane mapping: each issue = one s-row (256 f32 = 1KB)
    int bcs = l >> 2;                         // bc 0..15
    int dqs = (l & 3) ^ (bcs & 3);            // swizzled logical d-quad
    int bs  = (bcg * 16 + bcs) >> 4;
    int cs  = (bcg * 16 + bcs) & 15;
    const float* ubase = u + ((size_t)bs * SEQLEN + (size_t)cs * TC) * HID
                           + dg * 16 + dqs * 4;

    int nslab = 4 + 4 * th;   // lower t-half only needs s < 128

    f32x4 acc[2][8];
    #pragma unroll
    for (int dd = 0; dd < 2; dd++)
        #pragma unroll
        for (int tt = 0; tt < 8; tt++) { acc[dd][tt] = (f32x4){0.f,0.f,0.f,0.f}; }

    #define K3_STAGE(sk_, buf_)                                                   \
        {                                                                         \
            _Pragma("unroll")                                                     \
            for (int iq = 0; iq < 4; iq++) {                                      \
                int srow = w * 4 + iq;                                            \
                gload_lds16(ubase + (size_t)((sk_) * 32 + srow) * HID,            \
                            &ulds[buf_][srow * 256]);                             \
            }                                                                     \
        }

    K3_STAGE(0, 0);
    __syncthreads();

    // per-lane constant for KR index: i0 = L0 + sk*32 - tt*16
    int L0 = 255 - th * 128 + 8 * g - r16;

    for (int sk = 0; sk < nslab; sk++) {
        int cur = sk & 1;
        if (sk + 1 < nslab) K3_STAGE(sk + 1, cur ^ 1);
        #pragma unroll
        for (int dd = 0; dd < 2; dd++) {
            int dloc = w * 2 + dd;
            // B-frag: 8 strided LDS reads (quad-swizzled) + cvt to bf16
            int base_e = r16 * 16 + (((dloc >> 2) ^ (r16 & 3)) << 2) + (dloc & 3) + g * 8 * 256;
            bf16x8 B;
            #pragma unroll
            for (int j = 0; j < 8; j++)
                B[j] = (short)f2bf(ulds[cur][base_e + j * 256]);
            const unsigned short* krd = KR2 + (size_t)(dg * 16 + dloc) * 1056;
            #pragma unroll
            for (int tt = 0; tt < 8; tt++) {
                int i0 = L0 + sk * 32 - tt * 16;
                const unsigned short* ap = krd + (i0 & 1) * 528 + (i0 & ~1);
                bf16x8 A = (bf16x8)*(const bf16x8u*)ap;
                acc[dd][tt] = __builtin_amdgcn_mfma_f32_16x16x32_bf16(A, B, acc[dd][tt], 0, 0, 0);
            }
        }
        __syncthreads();
    }

    // state-init correction: acc += W2[t][n] x ZT[bc][n]
    #pragma unroll
    for (int dd = 0; dd < 2; dd++) {
        int d = dg * 16 + w * 2 + dd;
        const unsigned short* ztd = ZT + ((size_t)d * 128 + bcg * 16) * 64;
        const unsigned short* w2d = W2 + ((size_t)d * 256 + th * 128) * 64;
        #pragma unroll
        for (int ns = 0; ns < 2; ns++) {
            bf16x8 Bz = (bf16x8)*(const bf16x8u*)(ztd + (size_t)r16 * 64 + ns * 32 + 8 * g);
            #pragma unroll
            for (int tt = 0; tt < 8; tt++) {
                bf16x8 Aw = (bf16x8)*(const bf16x8u*)(w2d + (size_t)(tt * 16 + r16) * 64 + ns * 32 + 8 * g);
                acc[dd][tt] = __builtin_amdgcn_mfma_f32_16x16x32_bf16(Aw, Bz, acc[dd][tt], 0, 0, 0);
            }
        }
    }

    // epilogue: D layout col(n)=l&15 -> bc, row(m)=4*g+r -> t. Scattered 4B stores,
    // L2 combines (each 64B line filled entirely by this block's dg16).
    int bco = bcg * 16 + r16;
    int bo  = bco >> 4, co = bco & 15;
    #pragma unroll
    for (int dd = 0; dd < 2; dd++) {
        int d = dg * 16 + w * 2 + dd;
        #pragma unroll
        for (int tt = 0; tt < 8; tt++) {
            #pragma unroll
            for (int rr = 0; rr < 4; rr++) {
                int t = th * 128 + tt * 16 + g * 4 + rr;
                out[((size_t)bo * SEQLEN + (size_t)co * TC + t) * HID + d] = acc[dd][tt][rr];
            }
        }
    }
}

// ---------------------------------- fallback scalar K3 (round-10 best, 118 us)
__global__ __launch_bounds__(256, 3) void k3_scalar(const float* __restrict__ u,
                                                    const float* __restrict__ Dv,
                                                    const float* __restrict__ pa,
                                                    const float* __restrict__ pw,
                                                    const float* __restrict__ zl,
                                                    float* __restrict__ out) {
    __shared__ float utile[2][TT * DBLK];
    int bid  = blockIdx.x;
    int dset = bid & 15;
    int b    = (bid >> 4) & 7;
    int c    = bid >> 7;
    int w    = threadIdx.x >> 6;
    int lane = threadIdx.x & 63;
    int dl   = lane >> 2, p = lane & 3;
    int d    = dset * DBLK + w * 16 + dl;

    f32x2 a2[NP], w2[NP], z2[NP];
    {
        const f32x2* pap = (const f32x2*)(pa + (size_t)d * STATE + p * NS);
        const f32x2* pwp = (const f32x2*)(pw + (size_t)d * STATE + p * NS);
        #pragma unroll
        for (int j = 0; j < NP; j++) { a2[j] = pap[j]; w2[j] = pwp[j]; }
    }
    if (c == 0) {
        #pragma unroll
        for (int j = 0; j < NP; j++) { z2[j].x = 0.f; z2[j].y = 0.f; }
    } else {
        size_t stride = (size_t)BATCH * HID * STATE;
        const f32x2* zp = (const f32x2*)(zl + (size_t)(c - 1) * stride +
                                         ((size_t)b * HID + d) * STATE + p * NS);
        #pragma unroll
        for (int j = 0; j < NP; j++) z2[j] = zp[j];
    }

    float dvd = Dv[d];
    const char* ubase = (const char*)(u + ((size_t)b * SEQLEN + (size_t)c * TC) * HID
                                        + (size_t)dset * DBLK);
    float* po = out + ((size_t)b * SEQLEN + (size_t)c * TC) * HID + d;

    ISSUE_TILE(0, 0);
    __syncthreads();
    int cur = 0;
    for (int tile = 0; tile < NTILE; ++tile) {
        if (tile + 1 < NTILE) ISSUE_TILE(tile + 1, cur ^ 1);
        const float* ut = &utile[cur][w * 16 + dl];
        float* po_t = po + (size_t)tile * TT * HID;
        #pragma unroll
        for (int r0 = 0; r0 < TT; r0 += RB) {
            float ylane[RB], usv[RB];
            #pragma unroll
            for (int i = 0; i < RB; i++) {
                float uss = ut[(r0 + i) * DBLK];
                usv[i] = uss;
                f32x2 us; us.x = uss; us.y = uss;
                #pragma unroll
                for (int j = 0; j < NP; j++)
                    z2[j] = __builtin_elementwise_fma(a2[j], z2[j], us);
                f32x2 acc0 = z2[0] * w2[0];
                f32x2 acc1 = z2[1] * w2[1];
                #pragma unroll
                for (int j = 2; j < NP; j += 2) {
                    acc0 = __builtin_elementwise_fma(z2[j + 0], w2[j + 0], acc0);
                    acc1 = __builtin_elementwise_fma(z2[j + 1], w2[j + 1], acc1);
                }
                acc0 += acc1;
                ylane[i] = acc0.x + acc0.y;
            }
            #pragma unroll
            for (int i = 0; i < RB; i++) ylane[i] = quad_reduce_add(ylane[i]);
            #pragma unroll
            for (int i = 0; i < RB; i++)
                po_t[(size_t)(r0 + i) * HID] = fmaf(dvd, usv[i], ylane[i]);
        }
        __syncthreads();
        cur ^= 1;
    }
}

extern "C" void kernel_launch(void* const* d_in, const int* in_sizes, int n_in,
                              void* d_out, int out_size, void* d_ws, size_t ws_size,
                              hipStream_t stream) {
    const float* u  = (const float*)d_in[0];
    const float* A  = (const float*)d_in[1];
    const float* Bm = (const float*)d_in[2];
    const float* C  = (const float*)d_in[3];
    const float* Dv = (const float*)d_in[4];
    const float* dt = (const float*)d_in[5];
    float* out = (float*)d_out;

    char* ws = (char*)d_ws;
    float* pa = (float*)(ws + WS_PA);
    float* pw = (float*)(ws + WS_PW);
    float* pE = (float*)(ws + WS_PE);
    unsigned short* KR2 = (unsigned short*)(ws + WS_KR);
    float* zl = (float*)(ws + WS_ZL);
    unsigned short* ZT  = (unsigned short*)(ws + WS_ZT);
    unsigned short* W2  = (unsigned short*)(ws + WS_W2);

    k0_params<<<(HID * STATE) / 256, 256, 0, stream>>>(A, Bm, C, dt, pa, pw, pE);
    k1_locals<<<16 * 8 * (NC - 1), 256, 0, stream>>>(u, pa, zl);
    k2_scan<<<(BATCH * HID * STATE) / 256, 256, 0, stream>>>(pE, zl);

    if (ws_size >= WS_NEED) {
        k_kr<<<1024, 64, 0, stream>>>(pa, pw, Dv, KR2);
        k_w2<<<1024, 64, 0, stream>>>(pa, pw, W2);
        k_zt<<<(1024 * 128 * 64) / 256, 256, 0, stream>>>(zl, ZT);
        k3_mfma<<<64 * 8 * 2, 512, 0, stream>>>(u, KR2, W2, ZT, out);
    } else {
        k3_scalar<<<16 * 8 * NC, 256, 0, stream>>>(u, Dv, pa, pw, zl, out);
    }
}

// Round 12
// 275.010 us; speedup vs baseline: 1.5298x; 1.5298x over previous
//
#include <hip/hip_runtime.h>
#include <math.h>

#define BATCH  8
#define SEQLEN 4096
#define HID    1024
#define STATE  64
#define NC     16
#define TC     (SEQLEN / NC)   // 256 steps per chunk
#define TT     32              // time rows per LDS tile (k1/scalar path)
#define NTILE  (TC / TT)
#define DBLK   64
#define NS     16
#define NP     8
#define RB     8

typedef float f32x2 __attribute__((ext_vector_type(2)));
typedef float f32x4 __attribute__((ext_vector_type(4)));
typedef short bf16x8 __attribute__((ext_vector_type(8)));
typedef short bf16x8u __attribute__((ext_vector_type(8), aligned(4)));

// ws layout (bytes)
#define WS_PA  0
#define WS_PW  (256 * 1024)
#define WS_PE  (512 * 1024)
#define WS_KR  (1ull * 1024 * 1024)    // ushort[1024][2][528]  = 2.1 MB
#define WS_ZL  (4ull * 1024 * 1024)    // f32 [16][8][1024][64] = 32 MB
#define WS_ZT  (36ull * 1024 * 1024)   // ushort[1024][128][64] = 16 MB
#define WS_W2  (52ull * 1024 * 1024)   // ushort[1024][256][64] = 32 MB
#define WS_UBF (84ull * 1024 * 1024)   // ushort[8][16][1024][256] = 64 MB
#define WS_NEED (148ull * 1024 * 1024)

__device__ __forceinline__ unsigned int f2bf(float x) {
    unsigned int u = __builtin_bit_cast(unsigned int, x);
    u = (u + 0x7FFFu + ((u >> 16) & 1u)) >> 16;
    return u & 0xFFFFu;
}

__device__ __forceinline__ void gload_lds16(const void* g, void* l) {
    __builtin_amdgcn_global_load_lds((const __attribute__((address_space(1))) void*)g,
                                     (__attribute__((address_space(3))) void*)l,
                                     16, 0, 0);
}

__device__ __forceinline__ float quad_reduce_add(float y) {
    int t = __builtin_amdgcn_mov_dpp(__builtin_bit_cast(int, y), 0xB1, 0xF, 0xF, true);
    y += __builtin_bit_cast(float, t);
    t = __builtin_amdgcn_mov_dpp(__builtin_bit_cast(int, y), 0x4E, 0xF, 0xF, true);
    y += __builtin_bit_cast(float, t);
    return y;
}

// ---------------------------------------------------------------- K0: params
__global__ void k0_params(const float* __restrict__ A, const float* __restrict__ Bm,
                          const float* __restrict__ C, const float* __restrict__ dt,
                          float* __restrict__ pa, float* __restrict__ pw,
                          float* __restrict__ pE) {
    int i = blockIdx.x * 256 + threadIdx.x;
    if (i >= HID * STATE) return;
    int n = i & (STATE - 1);
    float aexp = expf(A[i]);
    float dtn  = dt[n];
    float a    = expf(-aexp * dtn);
    pa[i] = a;
    pw[i] = C[i] * (Bm[i] * (1.0f - a) / aexp);
    pE[i] = expf(-aexp * dtn * (float)TC);
}

// ------------------------------------------- kKR: reversed conv-kernel tables
__global__ void k_kr(const float* __restrict__ pa, const float* __restrict__ pw,
                     const float* __restrict__ Dv, unsigned short* __restrict__ KR2) {
    __shared__ float K[256];
    int d = blockIdx.x, n = threadIdx.x;
    float a = pa[d * 64 + n];
    float v = pw[d * 64 + n];
    float dvd = Dv[d];
    for (int t = 0; t < 256; t++) {
        float s = v;
        #pragma unroll
        for (int off = 1; off < 64; off <<= 1) s += __shfl_xor(s, off);
        if (n == 0) K[t] = s + (t == 0 ? dvd : 0.0f);
        v *= a;
    }
    __syncthreads();
    unsigned short* kd = KR2 + (size_t)d * 1056;
    for (int i = n; i < 528; i += 64) {
        int x0 = 255 - i;
        int x1 = 254 - i;
        kd[i]       = (x0 >= 0) ? (unsigned short)f2bf(K[x0]) : 0;
        kd[528 + i] = (x1 >= 0) ? (unsigned short)f2bf(K[x1]) : 0;
    }
}

// ------------------------------------------- kW2: W2[d][t][n] = w_n * a_n^{t+1}
__global__ void k_w2(const float* __restrict__ pa, const float* __restrict__ pw,
                     unsigned short* __restrict__ W2) {
    int d = blockIdx.x, n = threadIdx.x;
    float a = pa[d * 64 + n];
    float v = pw[d * 64 + n] * a;
    unsigned short* wd = W2 + (size_t)d * 256 * 64 + n;
    for (int t = 0; t < 256; t++) { wd[(size_t)t * 64] = (unsigned short)f2bf(v); v *= a; }
}

// ------------------------------------------- K1: chunk-local end states + ubfT
// block = (dset64, b, chunk c=0..15). Also emits u transposed to bf16:
// ubfT[b][c][d][t] (t contiguous), one rotating wave per tile, full 64B stores.
__global__ __launch_bounds__(256, 3) void k1_locals(const float* __restrict__ u,
                                                    const float* __restrict__ pa,
                                                    float* __restrict__ zl,
                                                    unsigned short* __restrict__ ubf) {
    __shared__ float utile[2][TT * DBLK];
    int bid  = blockIdx.x;
    int dset = bid & 15;
    int b    = (bid >> 4) & 7;
    int c    = bid >> 7;                    // 0..15
    int w    = threadIdx.x >> 6;
    int lane = threadIdx.x & 63;
    int dl   = lane >> 2, p = lane & 3;
    int d    = dset * DBLK + w * 16 + dl;

    f32x2 a2[NP], z2[NP];
    {
        const f32x2* pap = (const f32x2*)(pa + (size_t)d * STATE + p * NS);
        #pragma unroll
        for (int j = 0; j < NP; j++) a2[j] = pap[j];
    }
    #pragma unroll
    for (int j = 0; j < NP; j++) { z2[j].x = 0.f; z2[j].y = 0.f; }

    const char* ubase = (const char*)(u + ((size_t)b * SEQLEN + (size_t)c * TC) * HID
                                        + (size_t)dset * DBLK);

    #define ISSUE_TILE(t, buf)                                                        \
        {                                                                             \
            _Pragma("unroll")                                                         \
            for (int k = 0; k < 2; k++) {                                             \
                int off = w * 2048 + k * 1024 + lane * 16;                            \
                int row = off >> 8;                                                   \
                int col = off & 255;                                                  \
                const float* src = (const float*)(ubase + ((size_t)((t) * TT + row)) * (HID * 4) + col); \
                float* dst = &utile[buf][w * 512 + k * 256];                           \
                gload_lds16(src, dst);                                                \
            }                                                                         \
        }

    ISSUE_TILE(0, 0);
    __syncthreads();
    int cur = 0;
    for (int tile = 0; tile < NTILE; ++tile) {
        if (tile + 1 < NTILE) ISSUE_TILE(tile + 1, cur ^ 1);
        const float* ut = &utile[cur][w * 16 + dl];
        #pragma unroll
        for (int r = 0; r < TT; r++) {
            float uss = ut[r * DBLK];
            f32x2 us; us.x = uss; us.y = uss;
            #pragma unroll
            for (int j = 0; j < NP; j++)
                z2[j] = __builtin_elementwise_fma(a2[j], z2[j], us);
        }
        // rotating wave converts this tile to bf16, transposed [d][t], 64B rows
        if (ubf != nullptr && w == (tile & 3)) {
            const float* colp = &utile[cur][lane];     // column d = dset*64+lane
            unsigned int pk[16];
            #pragma unroll
            for (int q = 0; q < 16; q++) {
                unsigned int lo = f2bf(colp[(2 * q) * DBLK]);
                unsigned int hi = f2bf(colp[(2 * q + 1) * DBLK]);
                pk[q] = lo | (hi << 16);
            }
            size_t drow = (size_t)(b * 16 + c) * 1024 + dset * 64 + lane;
            unsigned int* dst = (unsigned int*)((char*)ubf + drow * 512 + (size_t)tile * 64);
            typedef unsigned int u32x4 __attribute__((ext_vector_type(4)));
            #pragma unroll
            for (int q = 0; q < 4; q++)
                *(u32x4*)(dst + q * 4) = (u32x4){pk[4*q], pk[4*q+1], pk[4*q+2], pk[4*q+3]};
        }
        __syncthreads();
        cur ^= 1;
    }

    f32x2* zp = (f32x2*)(zl + (((size_t)c * BATCH + b) * HID + d) * STATE + p * NS);
    #pragma unroll
    for (int j = 0; j < NP; j++) zp[j] = z2[j];
}

// ---------------------------------- K2: prefix scan over chunks
__global__ void k2_scan(const float* __restrict__ pE, float* __restrict__ zl) {
    int i  = blockIdx.x * 256 + threadIdx.x;
    int dn = i & (HID * STATE - 1);
    float E = pE[dn];
    size_t stride = (size_t)BATCH * HID * STATE;
    float g = zl[i];
    for (int c = 1; c < NC - 1; c++) {
        float v = zl[i + c * stride];
        g = fmaf(E, g, v);
        zl[i + c * stride] = g;
    }
}

// ---------------------------------- kZT: ZT[d][bc][n] bf16 chunk-init states
__global__ void k_zt(const float* __restrict__ zl, unsigned short* __restrict__ ZT) {
    int idx = blockIdx.x * 256 + threadIdx.x;
    int n  = idx & 63;
    int bc = (idx >> 6) & 127;
    int d  = idx >> 13;
    int b = bc >> 4, c = bc & 15;
    float z = 0.0f;
    if (c > 0)
        z = zl[((size_t)((c - 1) * 8 + b) * 1024 + d) * 64 + n];
    ZT[idx] = (unsigned short)f2bf(z);
}

// ---------------------------------- K3 MFMA: Toeplitz conv + state correction
// block: (dg 16-d, bcg 16-bc, th t-half). 512 thr = 8 waves; wave owns 2 d's.
// Staging: global_load_lds from ubfT with pre-swizzled sources -> conflict-free
// ds_read_b128 B-frags. Epilogue: LDS transpose -> full-line stores.
__global__ __launch_bounds__(512, 2) void k3_mfma(const unsigned short* __restrict__ ubf,
                                                  const unsigned short* __restrict__ KR2,
                                                  const unsigned short* __restrict__ W2,
                                                  const unsigned short* __restrict__ ZT,
                                                  float* __restrict__ out) {
    __shared__ __align__(16) char smem[2][16384];
    int bid = blockIdx.x;
    int th  = bid & 1;
    int bcg = (bid >> 1) & 7;
    int dg  = bid >> 4;                 // 0..63
    int tid = threadIdx.x;
    int w   = tid >> 6;                 // wave 0..7
    int l   = tid & 63;
    int g   = l >> 4;                   // 0..3
    int r16 = l & 15;

    int nslab = 4 + 4 * th;

    // staging sources: wave w, issue k -> bc = w*2+k; lane chunk l ->
    // d = (l>>2)^(bc&1), oct = (l&3)^((bc>>1)&3)  (inverse of read swizzle)
    const unsigned short* src01[2];
    #pragma unroll
    for (int k = 0; k < 2; k++) {
        int bc  = w * 2 + k;
        int dlc = (l >> 2) ^ (bc & 1);
        int oct = (l & 3) ^ ((bc >> 1) & 3);
        int gbc = bcg * 16 + bc;
        int bb = gbc >> 4, cc = gbc & 15;
        src01[k] = ubf + (((size_t)(bb * 16 + cc) * 1024 + dg * 16 + dlc) << 8) + oct * 8;
    }

    #define K3STAGE(sk_, buf_)                                                 \
        {                                                                      \
            _Pragma("unroll")                                                  \
            for (int k = 0; k < 2; k++) {                                      \
                char* dstp = &smem[buf_][(w * 2 + k) * 1024];                  \
                gload_lds16(src01[k] + (sk_) * 32, dstp);                      \
            }                                                                  \
        }

    // B-frag read bases (per dd): swizzled so 64 lanes cover 8x8 bank-quads
    int baseB[2];
    #pragma unroll
    for (int dd = 0; dd < 2; dd++) {
        int dlc = w * 2 + dd;
        baseB[dd] = r16 * 1024 + ((dlc ^ (r16 & 1)) * 64) + ((g ^ ((r16 >> 1) & 3)) * 16);
    }

    f32x4 acc[2][8];
    #pragma unroll
    for (int dd = 0; dd < 2; dd++)
        #pragma unroll
        for (int tt = 0; tt < 8; tt++) acc[dd][tt] = (f32x4){0.f, 0.f, 0.f, 0.f};

    K3STAGE(0, 0);
    __syncthreads();

    const unsigned short* krd0 = KR2 + (size_t)(dg * 16 + w * 2) * 1056;
    int L0 = 255 - th * 128 + 8 * g - r16;

    for (int sk = 0; sk < nslab; sk++) {
        int cur = sk & 1;
        if (sk + 1 < nslab) K3STAGE(sk + 1, cur ^ 1);
        #pragma unroll
        for (int dd = 0; dd < 2; dd++) {
            bf16x8 B = *(const bf16x8*)(&smem[cur][baseB[dd]]);
            const unsigned short* krd = krd0 + dd * 1056;
            #pragma unroll
            for (int tt = 0; tt < 8; tt++) {
                if (th * 128 + tt * 16 + 15 >= sk * 32) {   // triangular skip (uniform)
                    int i0 = L0 + sk * 32 - tt * 16;
                    bf16x8 A = (bf16x8)*(const bf16x8u*)(krd + (i0 & 1) * 528 + (i0 & ~1));
                    acc[dd][tt] = __builtin_amdgcn_mfma_f32_16x16x32_bf16(A, B, acc[dd][tt], 0, 0, 0);
                }
            }
        }
        __syncthreads();
    }

    // state-init correction: acc += W2[t][n] x ZT[bc][n]
    #pragma unroll
    for (int dd = 0; dd < 2; dd++) {
        int d = dg * 16 + w * 2 + dd;
        const unsigned short* ztd = ZT + ((size_t)d * 128 + bcg * 16) * 64;
        const unsigned short* w2d = W2 + ((size_t)d * 256 + th * 128) * 64;
        #pragma unroll
        for (int ns = 0; ns < 2; ns++) {
            bf16x8 Bz = (bf16x8)*(const bf16x8u*)(ztd + (size_t)r16 * 64 + ns * 32 + 8 * g);
            #pragma unroll
            for (int tt = 0; tt < 8; tt++) {
                bf16x8 Aw = (bf16x8)*(const bf16x8u*)(w2d + (size_t)(tt * 16 + r16) * 64 + ns * 32 + 8 * g);
                acc[dd][tt] = __builtin_amdgcn_mfma_f32_16x16x32_bf16(Aw, Bz, acc[dd][tt], 0, 0, 0);
            }
        }
    }

    // epilogue: LDS transpose (padded strides) -> full 64B-line stores
    float* eps = (float*)&smem[0][0];
    int rid = tid >> 1, half = tid & 1;
    int trow_r = rid >> 4, bc_r = rid & 15;
    int gbc_r = bcg * 16 + bc_r;
    int bo = gbc_r >> 4, co = gbc_r & 15;
    float* pbase = out + ((size_t)bo * SEQLEN + (size_t)co * TC + th * 128 + trow_r) * HID
                       + dg * 16 + half * 8;
    #pragma unroll
    for (int tt = 0; tt < 8; tt++) {
        __syncthreads();
        #pragma unroll
        for (int dd = 0; dd < 2; dd++) {
            #pragma unroll
            for (int rr = 0; rr < 4; rr++)
                eps[(g * 4 + rr) * 278 + r16 * 17 + (w * 2 + dd)] = acc[dd][tt][rr];
        }
        __syncthreads();
        f32x4 v0, v1;
        #pragma unroll
        for (int j = 0; j < 4; j++) v0[j] = eps[trow_r * 278 + bc_r * 17 + half * 8 + j];
        #pragma unroll
        for (int j = 0; j < 4; j++) v1[j] = eps[trow_r * 278 + bc_r * 17 + half * 8 + 4 + j];
        *(f32x4*)(pbase + (size_t)tt * 16 * HID)     = v0;
        *(f32x4*)(pbase + (size_t)tt * 16 * HID + 4) = v1;
    }
}

// ---------------------------------- fallback scalar K3 (round-10 best)
__global__ __launch_bounds__(256, 3) void k3_scalar(const float* __restrict__ u,
                                                    const float* __restrict__ Dv,
                                                    const float* __restrict__ pa,
                                                    const float* __restrict__ pw,
                                                    const float* __restrict__ zl,
                                                    float* __restrict__ out) {
    __shared__ float utile[2][TT * DBLK];
    int bid  = blockIdx.x;
    int dset = bid & 15;
    int b    = (bid >> 4) & 7;
    int c    = bid >> 7;
    int w    = threadIdx.x >> 6;
    int lane = threadIdx.x & 63;
    int dl   = lane >> 2, p = lane & 3;
    int d    = dset * DBLK + w * 16 + dl;

    f32x2 a2[NP], w2[NP], z2[NP];
    {
        const f32x2* pap = (const f32x2*)(pa + (size_t)d * STATE + p * NS);
        const f32x2* pwp = (const f32x2*)(pw + (size_t)d * STATE + p * NS);
        #pragma unroll
        for (int j = 0; j < NP; j++) { a2[j] = pap[j]; w2[j] = pwp[j]; }
    }
    if (c == 0) {
        #pragma unroll
        for (int j = 0; j < NP; j++) { z2[j].x = 0.f; z2[j].y = 0.f; }
    } else {
        size_t stride = (size_t)BATCH * HID * STATE;
        const f32x2* zp = (const f32x2*)(zl + (size_t)(c - 1) * stride +
                                         ((size_t)b * HID + d) * STATE + p * NS);
        #pragma unroll
        for (int j = 0; j < NP; j++) z2[j] = zp[j];
    }

    float dvd = Dv[d];
    const char* ubase = (const char*)(u + ((size_t)b * SEQLEN + (size_t)c * TC) * HID
                                        + (size_t)dset * DBLK);
    float* po = out + ((size_t)b * SEQLEN + (size_t)c * TC) * HID + d;

    ISSUE_TILE(0, 0);
    __syncthreads();
    int cur = 0;
    for (int tile = 0; tile < NTILE; ++tile) {
        if (tile + 1 < NTILE) ISSUE_TILE(tile + 1, cur ^ 1);
        const float* ut = &utile[cur][w * 16 + dl];
        float* po_t = po + (size_t)tile * TT * HID;
        #pragma unroll
        for (int r0 = 0; r0 < TT; r0 += RB) {
            float ylane[RB], usv[RB];
            #pragma unroll
            for (int i = 0; i < RB; i++) {
                float uss = ut[(r0 + i) * DBLK];
                usv[i] = uss;
                f32x2 us; us.x = uss; us.y = uss;
                #pragma unroll
                for (int j = 0; j < NP; j++)
                    z2[j] = __builtin_elementwise_fma(a2[j], z2[j], us);
                f32x2 acc0 = z2[0] * w2[0];
                f32x2 acc1 = z2[1] * w2[1];
                #pragma unroll
                for (int j = 2; j < NP; j += 2) {
                    acc0 = __builtin_elementwise_fma(z2[j + 0], w2[j + 0], acc0);
                    acc1 = __builtin_elementwise_fma(z2[j + 1], w2[j + 1], acc1);
                }
                acc0 += acc1;
                ylane[i] = acc0.x + acc0.y;
            }
            #pragma unroll
            for (int i = 0; i < RB; i++) ylane[i] = quad_reduce_add(ylane[i]);
            #pragma unroll
            for (int i = 0; i < RB; i++)
                po_t[(size_t)(r0 + i) * HID] = fmaf(dvd, usv[i], ylane[i]);
        }
        __syncthreads();
        cur ^= 1;
    }
}

extern "C" void kernel_launch(void* const* d_in, const int* in_sizes, int n_in,
                              void* d_out, int out_size, void* d_ws, size_t ws_size,
                              hipStream_t stream) {
    const float* u  = (const float*)d_in[0];
    const float* A  = (const float*)d_in[1];
    const float* Bm = (const float*)d_in[2];
    const float* C  = (const float*)d_in[3];
    const float* Dv = (const float*)d_in[4];
    const float* dt = (const float*)d_in[5];
    float* out = (float*)d_out;

    char* ws = (char*)d_ws;
    float* pa = (float*)(ws + WS_PA);
    float* pw = (float*)(ws + WS_PW);
    float* pE = (float*)(ws + WS_PE);
    unsigned short* KR2 = (unsigned short*)(ws + WS_KR);
    float* zl = (float*)(ws + WS_ZL);
    unsigned short* ZT  = (unsigned short*)(ws + WS_ZT);
    unsigned short* W2  = (unsigned short*)(ws + WS_W2);
    unsigned short* UBF = (unsigned short*)(ws + WS_UBF);

    bool mfma = (ws_size >= WS_NEED);

    k0_params<<<(HID * STATE) / 256, 256, 0, stream>>>(A, Bm, C, dt, pa, pw, pE);
    // k1: 16 dsets * 8 b * 16 chunks (all chunks: ubfT needs every chunk)
    k1_locals<<<16 * 8 * NC, 256, 0, stream>>>(u, pa, zl, mfma ? UBF : nullptr);
    k2_scan<<<(BATCH * HID * STATE) / 256, 256, 0, stream>>>(pE, zl);

    if (mfma) {
        k_kr<<<1024, 64, 0, stream>>>(pa, pw, Dv, KR2);
        k_w2<<<1024, 64, 0, stream>>>(pa, pw, W2);
        k_zt<<<(1024 * 128 * 64) / 256, 256, 0, stream>>>(zl, ZT);
        k3_mfma<<<64 * 8 * 2, 512, 0, stream>>>(UBF, KR2, W2, ZT, out);
    } else {
        k3_scalar<<<16 * 8 * NC, 256, 0, stream>>>(u, Dv, pa, pw, zl, out);
    }
}